// Round 1
// baseline (127.685 us; speedup 1.0000x reference)
//
#include <hip/hip_runtime.h>

#define D 4096
#define BLOCK 256
#define NROWS (8 * 2048)

// Block-wide 2-value sum reduction. 4 waves of 64 lanes.
// On return, a and b hold the block-wide sums in ALL threads.
__device__ __forceinline__ void block_reduce2(float& a, float& b, float* s_red, int t) {
    #pragma unroll
    for (int off = 32; off > 0; off >>= 1) {
        a += __shfl_down(a, off, 64);
        b += __shfl_down(b, off, 64);
    }
    const int wave = t >> 6;
    const int lane = t & 63;
    if (lane == 0) {
        s_red[wave * 2 + 0] = a;
        s_red[wave * 2 + 1] = b;
    }
    __syncthreads();
    a = s_red[0] + s_red[2] + s_red[4] + s_red[6];
    b = s_red[1] + s_red[3] + s_red[5] + s_red[7];
    __syncthreads();  // protect s_red before next iteration's writes
}

__global__ __launch_bounds__(BLOCK, 4) void sparsemax_kernel(
    const float* __restrict__ x, float* __restrict__ out) {
    __shared__ float s_red[8];

    const int row = blockIdx.x;
    const int t = threadIdx.x;
    const float4* __restrict__ xr =
        reinterpret_cast<const float4*>(x + (size_t)row * D);
    float4* __restrict__ outr = reinterpret_cast<float4*>(out + (size_t)row * D);

    // Load 16 elements per thread, coalesced float4 (16B/lane).
    float4 v[4];
    float s = 0.0f, dummy = 0.0f;
    #pragma unroll
    for (int j = 0; j < 4; ++j) {
        v[j] = xr[t + j * BLOCK];
        s += (v[j].x + v[j].y) + (v[j].z + v[j].w);
    }

    // Initial tau from full active set.
    block_reduce2(s, dummy, s_red, t);
    float tau = (s - 1.0f) / (float)D;
    float k_prev = (float)D;

    // Michelot fixed-point: active set shrinks monotonically; exact finite
    // termination when |{x_i > tau}| stops changing. All threads see the same
    // tau (broadcast via reduction), so the break is wave-uniform.
    for (int it = 0; it < 64; ++it) {
        float sum = 0.0f, cnt = 0.0f;
        #pragma unroll
        for (int j = 0; j < 4; ++j) {
            if (v[j].x > tau) { sum += v[j].x; cnt += 1.0f; }
            if (v[j].y > tau) { sum += v[j].y; cnt += 1.0f; }
            if (v[j].z > tau) { sum += v[j].z; cnt += 1.0f; }
            if (v[j].w > tau) { sum += v[j].w; cnt += 1.0f; }
        }
        block_reduce2(sum, cnt, s_red, t);
        const bool done = (cnt == k_prev);
        k_prev = cnt;
        tau = (sum - 1.0f) / cnt;
        if (done) break;
    }

    // out = max(x - tau, 0), vectorized stores.
    #pragma unroll
    for (int j = 0; j < 4; ++j) {
        float4 o;
        o.x = fmaxf(v[j].x - tau, 0.0f);
        o.y = fmaxf(v[j].y - tau, 0.0f);
        o.z = fmaxf(v[j].z - tau, 0.0f);
        o.w = fmaxf(v[j].w - tau, 0.0f);
        outr[t + j * BLOCK] = o;
    }
}

extern "C" void kernel_launch(void* const* d_in, const int* in_sizes, int n_in,
                              void* d_out, int out_size, void* d_ws, size_t ws_size,
                              hipStream_t stream) {
    const float* x = (const float*)d_in[0];
    float* out = (float*)d_out;
    sparsemax_kernel<<<NROWS, BLOCK, 0, stream>>>(x, out);
}

// Round 2
// 102.580 us; speedup vs baseline: 1.2447x; 1.2447x over previous
//
#include <hip/hip_runtime.h>

#define D 4096
#define BLOCK 256
#define NROWS (8 * 2048)
#define CAP 256
#define PADV (-3.0e38f)

// In-wave butterfly sum of two values; all 64 lanes end with the totals.
__device__ __forceinline__ void wave_reduce2_xor(float& a, float& b) {
    #pragma unroll
    for (int m = 1; m < 64; m <<= 1) {
        a += __shfl_xor(a, m, 64);
        b += __shfl_xor(b, m, 64);
    }
}

__global__ __launch_bounds__(BLOCK, 4) void sparsemax_kernel(
    const float* __restrict__ x, float* __restrict__ out) {
    __shared__ float s_red[8];
    __shared__ float s_act[CAP];
    __shared__ int s_cnt;

    const int row = blockIdx.x;
    const int t = threadIdx.x;
    const int wave = t >> 6;
    const int lane = t & 63;

    const float4* __restrict__ xr =
        reinterpret_cast<const float4*>(x + (size_t)row * D);
    float4* __restrict__ outr = reinterpret_cast<float4*>(out + (size_t)row * D);

    // Pass 1: load 16 elems/thread (coalesced float4), thread-local max.
    float4 v[4];
    float tmax = PADV;
    #pragma unroll
    for (int j = 0; j < 4; ++j) {
        v[j] = xr[t + j * BLOCK];
        tmax = fmaxf(tmax, fmaxf(fmaxf(v[j].x, v[j].y), fmaxf(v[j].z, v[j].w)));
    }

    if (t == 0) s_cnt = 0;

    // Block max: wave butterfly + 4-slot LDS combine.
    #pragma unroll
    for (int m = 1; m < 64; m <<= 1)
        tmax = fmaxf(tmax, __shfl_xor(tmax, m, 64));
    if (lane == 0) s_red[wave] = tmax;
    __syncthreads();  // also publishes s_cnt = 0
    const float rmax = fmaxf(fmaxf(s_red[0], s_red[1]), fmaxf(s_red[2], s_red[3]));

    // tau* >= rmax - 1 (since sum of (x - tau*)_+ = 1 >= rmax - tau*),
    // and tau* < rmax. So {x > rmax-1} is a superset of the support.
    const float tau0 = rmax - 1.0f;

    // Pass 2: compact candidates (x > tau0) into LDS (~16-40 expected).
    #pragma unroll
    for (int j = 0; j < 4; ++j) {
        const float e0 = v[j].x, e1 = v[j].y, e2 = v[j].z, e3 = v[j].w;
        if (e0 > tau0) { int i = atomicAdd(&s_cnt, 1); if (i < CAP) s_act[i] = e0; }
        if (e1 > tau0) { int i = atomicAdd(&s_cnt, 1); if (i < CAP) s_act[i] = e1; }
        if (e2 > tau0) { int i = atomicAdd(&s_cnt, 1); if (i < CAP) s_act[i] = e2; }
        if (e3 > tau0) { int i = atomicAdd(&s_cnt, 1); if (i < CAP) s_act[i] = e3; }
    }
    __syncthreads();
    const int cnt0 = s_cnt;  // uniform across block

    float tau = tau0;
    if (cnt0 <= CAP) {
        // Every wave redundantly runs Michelot on the compacted list:
        // no barriers, wave-local shuffles only. Identical fp sequence in
        // each wave -> identical tau.
        float a0 = (lane + 0   < cnt0) ? s_act[lane + 0]   : PADV;
        float a1 = (lane + 64  < cnt0) ? s_act[lane + 64]  : PADV;
        float a2 = (lane + 128 < cnt0) ? s_act[lane + 128] : PADV;
        float a3 = (lane + 192 < cnt0) ? s_act[lane + 192] : PADV;
        float k_prev = 1.0e30f;  // sentinel: first iteration never "done"
        for (int it = 0; it < 48; ++it) {
            float sum = 0.0f, cnt = 0.0f;
            if (a0 > tau) { sum += a0; cnt += 1.0f; }
            if (a1 > tau) { sum += a1; cnt += 1.0f; }
            if (a2 > tau) { sum += a2; cnt += 1.0f; }
            if (a3 > tau) { sum += a3; cnt += 1.0f; }
            wave_reduce2_xor(sum, cnt);
            if (cnt == k_prev) break;   // active set stable -> tau is final
            tau = (sum - 1.0f) / cnt;   // cnt >= 1 always (rmax stays active)
            k_prev = cnt;
        }
    } else {
        // Fallback (never hit for N(0,1) data): block-wide Michelot from tau0
        // over the full register tile.
        float k_prev = 1.0e30f;
        for (int it = 0; it < 64; ++it) {
            float sum = 0.0f, cnt = 0.0f;
            #pragma unroll
            for (int j = 0; j < 4; ++j) {
                if (v[j].x > tau) { sum += v[j].x; cnt += 1.0f; }
                if (v[j].y > tau) { sum += v[j].y; cnt += 1.0f; }
                if (v[j].z > tau) { sum += v[j].z; cnt += 1.0f; }
                if (v[j].w > tau) { sum += v[j].w; cnt += 1.0f; }
            }
            wave_reduce2_xor(sum, cnt);
            if (lane == 0) { s_red[wave * 2] = sum; s_red[wave * 2 + 1] = cnt; }
            __syncthreads();
            sum = s_red[0] + s_red[2] + s_red[4] + s_red[6];
            cnt = s_red[1] + s_red[3] + s_red[5] + s_red[7];
            __syncthreads();
            if (cnt == k_prev) break;
            tau = (sum - 1.0f) / cnt;
            k_prev = cnt;
        }
    }

    // Pass 3: out = max(x - tau, 0), vectorized stores from registers.
    #pragma unroll
    for (int j = 0; j < 4; ++j) {
        float4 o;
        o.x = fmaxf(v[j].x - tau, 0.0f);
        o.y = fmaxf(v[j].y - tau, 0.0f);
        o.z = fmaxf(v[j].z - tau, 0.0f);
        o.w = fmaxf(v[j].w - tau, 0.0f);
        outr[t + j * BLOCK] = o;
    }
}

extern "C" void kernel_launch(void* const* d_in, const int* in_sizes, int n_in,
                              void* d_out, int out_size, void* d_ws, size_t ws_size,
                              hipStream_t stream) {
    const float* x = (const float*)d_in[0];
    float* out = (float*)d_out;
    sparsemax_kernel<<<NROWS, BLOCK, 0, stream>>>(x, out);
}

// Round 4
// 69.933 us; speedup vs baseline: 1.8258x; 1.4668x over previous
//
#include <hip/hip_runtime.h>

#define D 4096
#define BLOCK 256
#define NROWS (8 * 2048)
#define CAP 256
#define PADV (-3.0e38f)

typedef float v4f __attribute__((ext_vector_type(4)));

// In-wave butterfly sum of two values; all 64 lanes end with the totals.
__device__ __forceinline__ void wave_reduce2_xor(float& a, float& b) {
    #pragma unroll
    for (int m = 1; m < 64; m <<= 1) {
        a += __shfl_xor(a, m, 64);
        b += __shfl_xor(b, m, 64);
    }
}

__global__ __launch_bounds__(BLOCK, 8) void sparsemax_kernel(
    const float* __restrict__ x, float* __restrict__ out) {
    __shared__ float s_red[8];
    __shared__ float s_act[CAP];
    __shared__ int s_cnt;

    const int row = blockIdx.x;
    const int t = threadIdx.x;
    const int wave = t >> 6;
    const int lane = t & 63;

    const v4f* __restrict__ xr =
        reinterpret_cast<const v4f*>(x + (size_t)row * D);
    v4f* __restrict__ outr = reinterpret_cast<v4f*>(out + (size_t)row * D);

    // Pass 1: load 16 elems/thread (coalesced 16B), thread-local max.
    // Regular (caching) loads: we WANT x resident in L2/L3 across replays.
    v4f v[4];
    float tmax = PADV;
    #pragma unroll
    for (int j = 0; j < 4; ++j) {
        v[j] = xr[t + j * BLOCK];
        tmax = fmaxf(tmax, fmaxf(fmaxf(v[j].x, v[j].y), fmaxf(v[j].z, v[j].w)));
    }

    if (t == 0) s_cnt = 0;

    // Block max: wave butterfly + 4-slot LDS combine.
    #pragma unroll
    for (int m = 1; m < 64; m <<= 1)
        tmax = fmaxf(tmax, __shfl_xor(tmax, m, 64));
    if (lane == 0) s_red[wave] = tmax;
    __syncthreads();  // also publishes s_cnt = 0
    const float rmax = fmaxf(fmaxf(s_red[0], s_red[1]), fmaxf(s_red[2], s_red[3]));

    // tau* >= rmax - 1 (since sum of (x - tau*)_+ = 1 >= rmax - tau*),
    // and tau* < rmax. So {x > rmax-1} is a superset of the support.
    const float tau0 = rmax - 1.0f;

    // Pass 2: compact candidates (x > tau0) into LDS (~16-40 expected).
    #pragma unroll
    for (int j = 0; j < 4; ++j) {
        const float e0 = v[j].x, e1 = v[j].y, e2 = v[j].z, e3 = v[j].w;
        if (e0 > tau0) { int i = atomicAdd(&s_cnt, 1); if (i < CAP) s_act[i] = e0; }
        if (e1 > tau0) { int i = atomicAdd(&s_cnt, 1); if (i < CAP) s_act[i] = e1; }
        if (e2 > tau0) { int i = atomicAdd(&s_cnt, 1); if (i < CAP) s_act[i] = e2; }
        if (e3 > tau0) { int i = atomicAdd(&s_cnt, 1); if (i < CAP) s_act[i] = e3; }
    }
    __syncthreads();
    const int cnt0 = s_cnt;  // uniform across block

    float tau = tau0;
    if (cnt0 <= CAP) {
        // Every wave redundantly runs Michelot on the compacted list:
        // no barriers, wave-local shuffles only. Identical fp sequence in
        // each wave -> identical tau.
        float a0 = (lane + 0   < cnt0) ? s_act[lane + 0]   : PADV;
        float a1 = (lane + 64  < cnt0) ? s_act[lane + 64]  : PADV;
        float a2 = (lane + 128 < cnt0) ? s_act[lane + 128] : PADV;
        float a3 = (lane + 192 < cnt0) ? s_act[lane + 192] : PADV;
        float k_prev = 1.0e30f;  // sentinel: first iteration never "done"
        for (int it = 0; it < 48; ++it) {
            float sum = 0.0f, cnt = 0.0f;
            if (a0 > tau) { sum += a0; cnt += 1.0f; }
            if (a1 > tau) { sum += a1; cnt += 1.0f; }
            if (a2 > tau) { sum += a2; cnt += 1.0f; }
            if (a3 > tau) { sum += a3; cnt += 1.0f; }
            wave_reduce2_xor(sum, cnt);
            if (cnt == k_prev) break;   // active set stable -> tau is final
            tau = (sum - 1.0f) / cnt;   // cnt >= 1 always (rmax stays active)
            k_prev = cnt;
        }
    } else {
        // Fallback (never hit for N(0,1) data): block-wide Michelot from tau0
        // over the full register tile.
        float k_prev = 1.0e30f;
        for (int it = 0; it < 64; ++it) {
            float sum = 0.0f, cnt = 0.0f;
            #pragma unroll
            for (int j = 0; j < 4; ++j) {
                if (v[j].x > tau) { sum += v[j].x; cnt += 1.0f; }
                if (v[j].y > tau) { sum += v[j].y; cnt += 1.0f; }
                if (v[j].z > tau) { sum += v[j].z; cnt += 1.0f; }
                if (v[j].w > tau) { sum += v[j].w; cnt += 1.0f; }
            }
            wave_reduce2_xor(sum, cnt);
            if (lane == 0) { s_red[wave * 2] = sum; s_red[wave * 2 + 1] = cnt; }
            __syncthreads();
            sum = s_red[0] + s_red[2] + s_red[4] + s_red[6];
            cnt = s_red[1] + s_red[3] + s_red[5] + s_red[7];
            __syncthreads();
            if (cnt == k_prev) break;
            tau = (sum - 1.0f) / cnt;
            k_prev = cnt;
        }
    }

    // Pass 3: out = max(x - tau, 0). Nontemporal stores: output is
    // write-once, never re-read -> don't evict x from L2/L3.
    #pragma unroll
    for (int j = 0; j < 4; ++j) {
        v4f o;
        o.x = fmaxf(v[j].x - tau, 0.0f);
        o.y = fmaxf(v[j].y - tau, 0.0f);
        o.z = fmaxf(v[j].z - tau, 0.0f);
        o.w = fmaxf(v[j].w - tau, 0.0f);
        __builtin_nontemporal_store(o, &outr[t + j * BLOCK]);
    }
}

extern "C" void kernel_launch(void* const* d_in, const int* in_sizes, int n_in,
                              void* d_out, int out_size, void* d_ws, size_t ws_size,
                              hipStream_t stream) {
    const float* x = (const float*)d_in[0];
    float* out = (float*)d_out;
    sparsemax_kernel<<<NROWS, BLOCK, 0, stream>>>(x, out);
}